// Round 13
// baseline (1043.129 us; speedup 1.0000x reference)
//
#include <hip/hip_runtime.h>

typedef unsigned short u16;
typedef unsigned int u32;
typedef __attribute__((ext_vector_type(4))) float f32x4;
typedef __attribute__((ext_vector_type(16))) float f32x16;
typedef __attribute__((ext_vector_type(8))) _Float16 half8;
typedef __attribute__((ext_vector_type(8))) unsigned short u16x8;
typedef __attribute__((ext_vector_type(4))) unsigned short u16x4;

static __device__ __forceinline__ u16 f2h(float f) {
  union { _Float16 h; u16 u; } c;
  c.h = (_Float16)f;
  return c.u;
}
static __device__ __forceinline__ float h2f(u16 u) {
  union { _Float16 h; u16 u; } c;
  c.u = u;
  return (float)c.h;
}
static __device__ __forceinline__ void gload_lds16(const void* g, void* l) {
  __builtin_amdgcn_global_load_lds((const __attribute__((address_space(1))) void*)g,
                                   (__attribute__((address_space(3))) void*)l,
                                   16, 0, 0);
}

// 16-lane reductions fully on the VALU pipe (DPP) — round-12 proven.
template <int CTRL>
static __device__ __forceinline__ float dppf(float x) {
  int i = __float_as_int(x);
  int r = __builtin_amdgcn_update_dpp(i, i, CTRL, 0xf, 0xf, true);
  return __int_as_float(r);
}
static __device__ __forceinline__ float red16_max(float v) {
  v = fmaxf(v, dppf<0xB1>(v));
  v = fmaxf(v, dppf<0x4E>(v));
  v = fmaxf(v, dppf<0x124>(v));
  v = fmaxf(v, dppf<0x128>(v));
  return v;
}
static __device__ __forceinline__ float red16_sum(float v) {
  v += dppf<0xB1>(v);
  v += dppf<0x4E>(v);
  v += dppf<0x124>(v);
  v += dppf<0x128>(v);
  return v;
}

// ---------------------------------------------------------------------------
// Transpose + f32->f16 convert: dst[c][r] = (f16) src[r][c].
// ---------------------------------------------------------------------------
__global__ __launch_bounds__(256) void transpose_cvt(const float* __restrict__ src,
                                                     u16* __restrict__ dst,
                                                     int R, int C) {
  __shared__ float tt[64][65];  // transposed tile: tt[c][r]
  const int t = threadIdx.x;
  const int c0 = blockIdx.x << 6, r0 = blockIdx.y << 6;
  const int r = t >> 4, cb = (t & 15) << 2;
#pragma unroll
  for (int i = 0; i < 4; ++i) {
    f32x4 v = *(const f32x4*)(src + (size_t)(r0 + r + i * 16) * C + c0 + cb);
#pragma unroll
    for (int j = 0; j < 4; ++j) tt[cb + j][r + i * 16] = v[j];
  }
  __syncthreads();
  const int cc = t >> 2, r8 = (t & 3) << 4;
  u16x8 o0, o1;
#pragma unroll
  for (int j = 0; j < 8; ++j) o0[j] = f2h(tt[cc][r8 + j]);
#pragma unroll
  for (int j = 0; j < 8; ++j) o1[j] = f2h(tt[cc][r8 + 8 + j]);
  u16* dp = dst + (size_t)(c0 + cc) * R + r0 + r8;
  *(u16x8*)dp = o0;
  *(u16x8*)(dp + 8) = o1;
}

// ---------------------------------------------------------------------------
// Elementwise f32 -> f16 convert (4 elems/thread)
// ---------------------------------------------------------------------------
__global__ __launch_bounds__(256) void cvt_f32_f16(const float* __restrict__ in,
                                                   u16* __restrict__ out, int n4) {
  int i = blockIdx.x * 256 + threadIdx.x;
  if (i >= n4) return;
  f32x4 v = *(const f32x4*)(in + (size_t)i * 4);
  u16x4 o;
  o[0] = f2h(v[0]); o[1] = f2h(v[1]); o[2] = f2h(v[2]); o[3] = f2h(v[3]);
  *(u16x4*)(out + (size_t)i * 4) = o;
}

// ---------------------------------------------------------------------------
// 256x256 GEMM, double-buffered LDS, single barrier per K-tile — now on
// mfma_f32_32x32x16_f16 (higher matrix-pipe rate, half the MFMA instrs).
// Per wave (2Mx4N decomposition): 128x64 output = 4 m-frags x 2 n-frags of
// 32x32, K-tile 64 = 4 k-steps of 16. A/B lane layout: row = lane&31,
// k = (lane>>5)*8 + e (16B contiguous). C/D: col=lane&31,
// row=(reg&3)+8*(reg>>2)+4*(lane>>5) -> each f32x4 group = 4 contiguous rows.
// ---------------------------------------------------------------------------
static __device__ __forceinline__ void store_out(float* C, size_t idx, float v) { C[idx] = v; }
static __device__ __forceinline__ void store_out(u16* C, size_t idx, float v) { C[idx] = f2h(v); }

static __device__ __forceinline__ void stageA(const u16* __restrict__ Ab, int K, int kt,
                                              u16* As, int mh, int t) {
  int hf = t >> 8;
  int tt = t & 255;
  int row = hf * 128 + mh * 32 + (tt >> 3);
  int slot = tt & 7;
  gload_lds16(Ab + (size_t)row * K + kt + ((slot ^ (row & 7)) << 3),
              (char*)As + hf * 16384 + mh * 4096 + tt * 16);
}
static __device__ __forceinline__ void stageB(const u16* __restrict__ Bb, int K, int kt,
                                              u16* Bs, int j, int t) {
  int row = j * 64 + (t >> 3);
  int slot = t & 7;
  gload_lds16(Bb + (size_t)row * K + kt + ((slot ^ (row & 7)) << 3),
              (char*)Bs + j * 8192 + t * 16);
}

// bf[nf][ks]: B fragment, rows wn*64 + nf*32 + l31, k-step ks
#define LOAD_BF32(BS)                                                            \
  _Pragma("unroll") for (int nf = 0; nf < 2; ++nf)                               \
    _Pragma("unroll") for (int ks = 0; ks < 4; ++ks) {                           \
      int row = wn * 64 + nf * 32 + l31;                                         \
      int slot = (ks * 2 + hi) ^ (l31 & 7);                                      \
      bf[nf][ks] = *(const half8*)((const char*)(BS) + row * 128 + slot * 16);   \
    }

#define LOAD_AF32(AF, AS, MF)                                                    \
  _Pragma("unroll") for (int ks = 0; ks < 4; ++ks) {                             \
    int row = wm * 128 + (MF) * 32 + l31;                                        \
    int slot = (ks * 2 + hi) ^ (l31 & 7);                                        \
    (AF)[ks] = *(const half8*)((const char*)(AS) + row * 128 + slot * 16);       \
  }

#define MFMA_BURST32(AF, MF)                                                     \
  __builtin_amdgcn_s_setprio(1);                                                 \
  _Pragma("unroll") for (int ks = 0; ks < 4; ++ks)                               \
    _Pragma("unroll") for (int nf = 0; nf < 2; ++nf)                             \
      acc[MF][nf] = __builtin_amdgcn_mfma_f32_32x32x16_f16(                      \
          (AF)[ks], bf[nf][ks], acc[MF][nf], 0, 0, 0);                           \
  __builtin_amdgcn_s_setprio(0);

template <typename OutT>
__global__ __launch_bounds__(512, 2) void gemm256(const u16* __restrict__ A,
                                                  const u16* __restrict__ Bt,
                                                  OutT* __restrict__ C,
                                                  u16* __restrict__ vtg,
                                                  const float* __restrict__ ropeTab,
                                                  int M, int N, int K, int nbn,
                                                  int ldc) {
  __shared__ u16 lds[4][16384];
  const int t = threadIdx.x;
  const int lane = t & 63;
  const int wid = t >> 6;
  const int l31 = lane & 31, hi = lane >> 5;
  const int wm = wid >> 2, wn = wid & 3;
  const int nwg = gridDim.x;
  const int bid = blockIdx.x;
  const int wgid = (bid & 7) * (nwg >> 3) + (bid >> 3);  // XCD swizzle (nwg%8==0)
  const int bm = wgid / nbn, bn = wgid % nbn;
  const u16* Ab = A + (size_t)bm * 256 * K;
  const u16* Bb = Bt + (size_t)bn * 256 * K;
  f32x16 acc[4][2] = {};

  stageA(Ab, K, 0, lds[0], 0, t);
  stageA(Ab, K, 0, lds[0], 1, t);
  stageA(Ab, K, 0, lds[0], 2, t);
  stageA(Ab, K, 0, lds[0], 3, t);
  stageB(Bb, K, 0, lds[1], 0, t);
  stageB(Bb, K, 0, lds[1], 1, t);
  stageB(Bb, K, 0, lds[1], 2, t);
  stageB(Bb, K, 0, lds[1], 3, t);
  asm volatile("s_waitcnt vmcnt(0)" ::: "memory");
  __builtin_amdgcn_s_barrier();

  const int nt = K >> 6;
  for (int i = 0; i < nt; ++i) {
    u16* As  = lds[(i & 1) << 1];
    u16* Bs  = lds[((i & 1) << 1) + 1];
    u16* Asn = lds[((i + 1) & 1) << 1];
    u16* Bsn = lds[(((i + 1) & 1) << 1) + 1];
    int k1 = (i + 1) << 6; if (k1 >= K) k1 = 0;  // tail: staged, never read
    half8 bf[2][4], afA[4], afB[4];
    LOAD_BF32(Bs);
    LOAD_AF32(afA, As, 0);
    stageB(Bb, K, k1, Bsn, 0, t);
    stageB(Bb, K, k1, Bsn, 1, t);
    stageB(Bb, K, k1, Bsn, 2, t);
    stageB(Bb, K, k1, Bsn, 3, t);
    stageA(Ab, K, k1, Asn, 0, t);
    stageA(Ab, K, k1, Asn, 1, t);
    stageA(Ab, K, k1, Asn, 2, t);
    stageA(Ab, K, k1, Asn, 3, t);
    LOAD_AF32(afB, As, 1);
    MFMA_BURST32(afA, 0);
    LOAD_AF32(afA, As, 2);
    MFMA_BURST32(afB, 1);
    LOAD_AF32(afB, As, 3);
    MFMA_BURST32(afA, 2);
    MFMA_BURST32(afB, 3);
    asm volatile("s_waitcnt vmcnt(0) lgkmcnt(0)" ::: "memory");
    __builtin_amdgcn_s_barrier();
  }

  if (vtg && bn >= 32) {
    // V part: store transposed into vtg[b][h][d][t], 4 consecutive t per lane
#pragma unroll
    for (int mf = 0; mf < 4; ++mf) {
#pragma unroll
      for (int q = 0; q < 4; ++q) {
        int row0 = bm * 256 + wm * 128 + mf * 32 + q * 8 + 4 * hi;
        int bI = row0 >> 11, t0 = row0 & 2047;
#pragma unroll
        for (int nf = 0; nf < 2; ++nf) {
          int vcol = bn * 256 + wn * 64 + nf * 32 + l31 - 8192;
          int hI = vcol >> 7, dI = vcol & 127;
          u16x4 o;
#pragma unroll
          for (int rr = 0; rr < 4; ++rr) o[rr] = f2h(acc[mf][nf][q * 4 + rr]);
          *(u16x4*)(vtg + ((size_t)(bI * 32 + hI) * 128 + dI) * 2048 + t0) = o;
        }
      }
    }
  } else {
    if (ropeTab) {
      const bool even = (lane & 1) == 0;
#pragma unroll
      for (int mf = 0; mf < 4; ++mf) {
#pragma unroll
        for (int q = 0; q < 4; ++q) {
          int row0 = bm * 256 + wm * 128 + mf * 32 + q * 8 + 4 * hi;
#pragma unroll
          for (int nf = 0; nf < 2; ++nf) {
            int col = bn * 256 + wn * 64 + nf * 32 + l31;
            int p = (col & 127) >> 1;
#pragma unroll
            for (int rr = 0; rr < 4; ++rr) {
              int tpos = (row0 + rr) & 2047;
              float ang = ropeTab[tpos * 64 + p];
              float sn, cs;
              __sincosf(ang, &sn, &cs);
              float own = acc[mf][nf][q * 4 + rr];
              float xp = __shfl_xor(own, 1, 64);
              acc[mf][nf][q * 4 + rr] = even ? (own * cs - xp * sn)
                                             : (xp * sn + own * cs);
            }
          }
        }
      }
    }
#pragma unroll
    for (int mf = 0; mf < 4; ++mf) {
#pragma unroll
      for (int q = 0; q < 4; ++q) {
        int row0 = bm * 256 + wm * 128 + mf * 32 + q * 8 + 4 * hi;
#pragma unroll
        for (int nf = 0; nf < 2; ++nf) {
          int col = bn * 256 + wn * 64 + nf * 32 + l31;
#pragma unroll
          for (int rr = 0; rr < 4; ++rr)
            store_out(C, (size_t)(row0 + rr) * ldc + col, acc[mf][nf][q * 4 + rr]);
        }
      }
    }
  }
}

// ---------------------------------------------------------------------------
// Adapter k/v: acc[j,n] = sum_k prompt[j,k] * w_attn[k, 4096+n]
// ---------------------------------------------------------------------------
__global__ __launch_bounds__(256) void adaption_kv_kernel(const float* __restrict__ prompt,
                                                          const float* __restrict__ w_attn,
                                                          u16* __restrict__ akbuf,
                                                          u16* __restrict__ avbuf) {
  __shared__ float pl[10][512];
  __shared__ float red[8][10][32];
  const int t = threadIdx.x;
  const int tc = t & 31, tk = t >> 5;
  const int n = blockIdx.x * 32 + tc;  // 0..8191
  float acc[10] = {};
  for (int k0 = 0; k0 < 4096; k0 += 512) {
    __syncthreads();
#pragma unroll
    for (int i = 0; i < 20; ++i) {
      int idx = t + 256 * i;  // < 5120
      int j = idx >> 9, kk = idx & 511;
      pl[j][kk] = prompt[(size_t)j * 4096 + k0 + kk];
    }
    __syncthreads();
    for (int kk = tk; kk < 512; kk += 8) {
      float wv = w_attn[(size_t)(k0 + kk) * 12288 + 4096 + n];
#pragma unroll
      for (int j = 0; j < 10; ++j) acc[j] += pl[j][kk] * wv;
    }
  }
  __syncthreads();
#pragma unroll
  for (int j = 0; j < 10; ++j) red[tk][j][tc] = acc[j];
  __syncthreads();
  if (tk == 0) {
    float s[10];
#pragma unroll
    for (int j = 0; j < 10; ++j) {
      s[j] = 0.f;
#pragma unroll
      for (int q = 0; q < 8; ++q) s[j] += red[q][j][tc];
    }
    u16* dst;
    int hh, d;
    if (n < 4096) { dst = akbuf; hh = n >> 7; d = n & 127; }
    else          { dst = avbuf; hh = (n - 4096) >> 7; d = n & 127; }
#pragma unroll
    for (int j = 0; j < 16; ++j)
      dst[(size_t)(hh * 16 + j) * 128 + d] = (j < 10) ? f2h(s[j]) : (u16)0;
  }
}

// ---------------------------------------------------------------------------
// Flash attention + adapter epilogue (round-12 known-good, unchanged).
// 4 waves, 64 q rows/block, KV tile 64. LDS 40KB -> 4 blocks/CU. DPP softmax.
// ---------------------------------------------------------------------------
__global__ __launch_bounds__(256) void attn_kernel(const u16* __restrict__ qk,
                                                   const u16* __restrict__ vt,
                                                   const u16* __restrict__ akbuf,
                                                   const u16* __restrict__ avbuf,
                                                   const float* __restrict__ gating,
                                                   u16* __restrict__ y) {
  __shared__ u16 Kl[64 * 128];
  __shared__ u16 Vtl[128 * 64];
  __shared__ u16 Pl[4][16 * 64];

  const int t = threadIdx.x;
  const int lane = t & 63, w = t >> 6;
  const int g = lane >> 4, l15 = lane & 15;
  const int bx = blockIdx.x;
  const int qb = 31 - (bx >> 6);          // long blocks first
  const int bh = bx & 63, b = bh >> 5, h = bh & 31;
  const int ldq = 8192;
  const u16* Qg = qk + (size_t)b * 2048 * ldq + h * 128;
  const u16* Kg = Qg + 4096;
  const u16* VtG = vt + (size_t)(b * 32 + h) * 128 * 2048;
  u16* AKb = &Pl[0][0];

  // stage Q (64x128) into Kl and AK (16x128) into P region via global_load_lds
#pragma unroll
  for (int i = 0; i < 4; ++i) {
    int c = t + 256 * i;
    int row = c >> 4, slot = c & 15;
    gload_lds16(Qg + (size_t)(qb * 64 + row) * ldq + ((slot ^ (row & 15)) << 3),
                (char*)Kl + c * 16);
  }
  {
    int row = t >> 4, slot = t & 15;
    gload_lds16(akbuf + (size_t)(h * 16 + row) * 128 + ((slot ^ row) << 3),
                (char*)AKb + t * 16);
  }
  __syncthreads();

  half8 qf[4];
#pragma unroll
  for (int kk = 0; kk < 4; ++kk) {
    int slot = (kk * 4 + g) ^ l15;
    qf[kk] = *(const half8*)((const char*)Kl + (w * 16 + l15) * 256 + (slot << 4));
  }
  f32x4 sa = {};
#pragma unroll
  for (int kk = 0; kk < 4; ++kk) {
    int slot = (kk * 4 + g) ^ l15;
    half8 af = *(const half8*)((const char*)AKb + l15 * 256 + (slot << 4));
    sa = __builtin_amdgcn_mfma_f32_16x16x32_f16(qf[kk], af, sa, 0, 0, 0);
  }
  __syncthreads();

  f32x4 acc[8] = {};
  float mrun[4], lrun[4];
#pragma unroll
  for (int r = 0; r < 4; ++r) { mrun[r] = -1e30f; lrun[r] = 0.f; }

  for (int kvt = 0; kvt <= qb; ++kvt) {
#pragma unroll
    for (int i = 0; i < 4; ++i) {
      int c = t + 256 * i;
      int row = c >> 4, slot = c & 15;
      gload_lds16(Kg + (size_t)(kvt * 64 + row) * ldq + ((slot ^ (row & 15)) << 3),
                  (char*)Kl + c * 16);
    }
#pragma unroll
    for (int i = 0; i < 4; ++i) {
      int c = t + 256 * i;
      int d = c >> 3, s3 = c & 7;
      gload_lds16(VtG + (size_t)d * 2048 + kvt * 64 + ((s3 ^ (d & 7)) << 3),
                  (char*)Vtl + c * 16);
    }
    __syncthreads();

    f32x4 s[4] = {};
#pragma unroll
    for (int nf = 0; nf < 4; ++nf) {
#pragma unroll
      for (int kk = 0; kk < 4; ++kk) {
        int slot = (kk * 4 + g) ^ l15;
        half8 kf = *(const half8*)((const char*)Kl + (nf * 16 + l15) * 256 + (slot << 4));
        s[nf] = __builtin_amdgcn_mfma_f32_16x16x32_f16(qf[kk], kf, s[nf], 0, 0, 0);
      }
    }
    const float sc = 0.08838834764831843f;  // 1/sqrt(128)
    if (kvt == qb) {
#pragma unroll
      for (int nf = 0; nf < 4; ++nf)
#pragma unroll
        for (int r = 0; r < 4; ++r) {
          int kv = nf * 16 + l15;
          int qq = w * 16 + 4 * g + r;
          float v = s[nf][r] * sc;
          s[nf][r] = (kv <= qq) ? v : -1e30f;
        }
    } else {
#pragma unroll
      for (int nf = 0; nf < 4; ++nf)
#pragma unroll
        for (int r = 0; r < 4; ++r) s[nf][r] *= sc;
    }

    // online softmax: 16-lane reduce fully on VALU (DPP)
    float alpha[4];
#pragma unroll
    for (int r = 0; r < 4; ++r) {
      float mt = fmaxf(fmaxf(s[0][r], s[1][r]), fmaxf(s[2][r], s[3][r]));
      mt = red16_max(mt);
      float mn = fmaxf(mrun[r], mt);
      alpha[r] = __expf(mrun[r] - mn);
      mrun[r] = mn;
      float rs = 0.f;
#pragma unroll
      for (int nf = 0; nf < 4; ++nf) {
        float p = __expf(s[nf][r] - mn);
        s[nf][r] = p;
        rs += p;
      }
      rs = red16_sum(rs);
      lrun[r] = lrun[r] * alpha[r] + rs;
    }
#pragma unroll
    for (int nd = 0; nd < 8; ++nd)
#pragma unroll
      for (int r = 0; r < 4; ++r)
        acc[nd][r] *= alpha[r];

#pragma unroll
    for (int nf = 0; nf < 4; ++nf)
#pragma unroll
      for (int r = 0; r < 4; ++r) {
        int qq = 4 * g + r;
        int kv = nf * 16 + l15;
        int byteoff = (qq * 128 + kv * 2) ^ ((qq & 7) << 4);
        *(u16*)((char*)Pl[w] + byteoff) = f2h(s[nf][r]);
      }

#pragma unroll
    for (int kk2 = 0; kk2 < 2; ++kk2) {
      int pslot = (kk2 * 4 + g) ^ (l15 & 7);
      half8 pf = *(const half8*)((const char*)Pl[w] + l15 * 128 + (pslot << 4));
#pragma unroll
      for (int nd = 0; nd < 8; ++nd) {
        int d = nd * 16 + l15;
        int slot = (kk2 * 4 + g) ^ (d & 7);
        half8 vf = *(const half8*)((const char*)Vtl + d * 128 + (slot << 4));
        acc[nd] = __builtin_amdgcn_mfma_f32_16x16x32_f16(pf, vf, acc[nd], 0, 0, 0);
      }
    }
    __syncthreads();
  }

  // ---- epilogue ----
  {
    int d = t >> 1;
    int jb = (t & 1) << 4;
#pragma unroll
    for (int i = 0; i < 16; ++i) {
      int j = jb + i;
      u16 v = (j < 16) ? avbuf[(size_t)(h * 16 + j) * 128 + d] : (u16)0;
      int byteoff = (d * 64 + j * 2) ^ ((d & 3) << 4);
      *(u16*)((char*)Kl + byteoff) = v;
    }
  }
  __syncthreads();

  float ga = gating[0];
  float pa4[4];
#pragma unroll
  for (int r = 0; r < 4; ++r) {
    float v = sa[r] * (1.0f / 64.0f);
    if (l15 >= 10) v = -1e30f;
    float mt = red16_max(v);
    float p = __expf(v - mt);
    float rs = red16_sum(p);
    pa4[r] = p / rs * ga;
  }
#pragma unroll
  for (int r = 0; r < 4; ++r) {
    float inv = 1.0f / lrun[r];
#pragma unroll
    for (int nd = 0; nd < 8; ++nd)
      acc[nd][r] *= inv;
  }
#pragma unroll
  for (int r = 0; r < 4; ++r) {
    int qq = 4 * g + r;
    int b1 = (qq * 128 + l15 * 2) ^ ((qq & 7) << 4);
    *(u16*)((char*)Pl[w] + b1) = f2h(pa4[r]);
    int b2 = (qq * 128 + (16 + l15) * 2) ^ ((qq & 7) << 4);
    *(u16*)((char*)Pl[w] + b2) = 0;
  }
  {
    int pslot = g ^ (l15 & 7);
    half8 pf = *(const half8*)((const char*)Pl[w] + l15 * 128 + (pslot << 4));
#pragma unroll
    for (int nd = 0; nd < 8; ++nd) {
      int d = nd * 16 + l15;
      int byteoff = (d * 64 + g * 16) ^ ((d & 3) << 4);
      half8 avf = *(const half8*)((const char*)Kl + byteoff);
      acc[nd] = __builtin_amdgcn_mfma_f32_16x16x32_f16(pf, avf, acc[nd], 0, 0, 0);
    }
  }
#pragma unroll
  for (int nd = 0; nd < 8; ++nd) {
    int col = h * 128 + nd * 16 + l15;
#pragma unroll
    for (int r = 0; r < 4; ++r) {
      int row = qb * 64 + w * 16 + 4 * g + r;
      y[(size_t)(b * 2048 + row) * 4096 + col] = f2h(acc[nd][r]);
    }
  }
}

// ---------------------------------------------------------------------------
extern "C" void kernel_launch(void* const* d_in, const int* in_sizes, int n_in,
                              void* d_out, int out_size, void* d_ws, size_t ws_size,
                              hipStream_t stream) {
  (void)in_sizes; (void)n_in; (void)out_size; (void)ws_size;
  const float* x      = (const float*)d_in[0];
  const float* prompt = (const float*)d_in[1];
  const float* rope   = (const float*)d_in[2];
  const float* w_attn = (const float*)d_in[3];
  const float* w_proj = (const float*)d_in[4];
  const float* gating = (const float*)d_in[5];
  float* out = (float*)d_out;

  char* ws = (char*)d_ws;
  u16* WtA = (u16*)(ws);                     // 12288x4096 f16 (100663296 B)
  u16* Yb  = (u16*)(ws);                     // reuses WtA region after GEMM1
  u16* qk  = (u16*)(ws + 100663296);         // 4096x8192 f16 (67108864 B)
  u16* VtG = (u16*)(ws + 167772160);         // 2x32x128x2048 f16 (33554432 B)
  u16* xb  = (u16*)(ws + 201326592);         // 4096x4096 f16
  u16* WtP = (u16*)(ws + 201326592);         // reuses xb region after GEMM1
  u16* akb = (u16*)(ws + 234881024);         // 32x16x128 f16
  u16* avb = (u16*)(ws + 234881024 + 131072);

  transpose_cvt<<<dim3(192, 64), dim3(256), 0, stream>>>(w_attn, WtA, 4096, 12288);
  cvt_f32_f16<<<dim3(16384), dim3(256), 0, stream>>>(x, xb, 4194304);
  gemm256<u16><<<dim3(768), dim3(512), 0, stream>>>(xb, WtA, qk, VtG, rope,
                                                    4096, 12288, 4096, 48, 8192);
  adaption_kv_kernel<<<dim3(256), dim3(256), 0, stream>>>(prompt, w_attn, akb, avb);
  attn_kernel<<<dim3(2048), dim3(256), 0, stream>>>(qk, VtG, akb, avb, gating, Yb);
  transpose_cvt<<<dim3(64, 64), dim3(256), 0, stream>>>(w_proj, WtP, 4096, 4096);
  gemm256<float><<<dim3(256), dim3(512), 0, stream>>>(Yb, WtP, out, nullptr, nullptr,
                                                      4096, 4096, 4096, 16, 4096);
}

// Round 14
// 956.160 us; speedup vs baseline: 1.0910x; 1.0910x over previous
//
#include <hip/hip_runtime.h>

typedef unsigned short u16;
typedef unsigned int u32;
typedef __attribute__((ext_vector_type(4))) float f32x4;
typedef __attribute__((ext_vector_type(8))) _Float16 half8;
typedef __attribute__((ext_vector_type(8))) unsigned short u16x8;
typedef __attribute__((ext_vector_type(4))) unsigned short u16x4;

static __device__ __forceinline__ u16 f2h(float f) {
  union { _Float16 h; u16 u; } c;
  c.h = (_Float16)f;
  return c.u;
}
static __device__ __forceinline__ float h2f(u16 u) {
  union { _Float16 h; u16 u; } c;
  c.u = u;
  return (float)c.h;
}
static __device__ __forceinline__ void gload_lds16(const void* g, void* l) {
  __builtin_amdgcn_global_load_lds((const __attribute__((address_space(1))) void*)g,
                                   (__attribute__((address_space(3))) void*)l,
                                   16, 0, 0);
}

// DPP helpers (VALU pipe, no LDS port). 0xB1 = quad_perm swap-neighbor (lane^1),
// 0x4E = swap-pair (lane^2), 0x124/0x128 = row_ror:4/8 — all proven on this
// problem (rounds 6/12).
template <int CTRL>
static __device__ __forceinline__ float dppf(float x) {
  int i = __float_as_int(x);
  int r = __builtin_amdgcn_update_dpp(i, i, CTRL, 0xf, 0xf, true);
  return __int_as_float(r);
}
static __device__ __forceinline__ float red16_max(float v) {
  v = fmaxf(v, dppf<0xB1>(v));
  v = fmaxf(v, dppf<0x4E>(v));
  v = fmaxf(v, dppf<0x124>(v));
  v = fmaxf(v, dppf<0x128>(v));
  return v;
}
static __device__ __forceinline__ float red16_sum(float v) {
  v += dppf<0xB1>(v);
  v += dppf<0x4E>(v);
  v += dppf<0x124>(v);
  v += dppf<0x128>(v);
  return v;
}

// ---------------------------------------------------------------------------
// Transpose + f32->f16 convert: dst[c][r] = (f16) src[r][c].
// ---------------------------------------------------------------------------
__global__ __launch_bounds__(256) void transpose_cvt(const float* __restrict__ src,
                                                     u16* __restrict__ dst,
                                                     int R, int C) {
  __shared__ float tt[64][65];  // transposed tile: tt[c][r]
  const int t = threadIdx.x;
  const int c0 = blockIdx.x << 6, r0 = blockIdx.y << 6;
  const int r = t >> 4, cb = (t & 15) << 2;
#pragma unroll
  for (int i = 0; i < 4; ++i) {
    f32x4 v = *(const f32x4*)(src + (size_t)(r0 + r + i * 16) * C + c0 + cb);
#pragma unroll
    for (int j = 0; j < 4; ++j) tt[cb + j][r + i * 16] = v[j];
  }
  __syncthreads();
  const int cc = t >> 2, r8 = (t & 3) << 4;
  u16x8 o0, o1;
#pragma unroll
  for (int j = 0; j < 8; ++j) o0[j] = f2h(tt[cc][r8 + j]);
#pragma unroll
  for (int j = 0; j < 8; ++j) o1[j] = f2h(tt[cc][r8 + 8 + j]);
  u16* dp = dst + (size_t)(c0 + cc) * R + r0 + r8;
  *(u16x8*)dp = o0;
  *(u16x8*)(dp + 8) = o1;
}

// ---------------------------------------------------------------------------
// Elementwise f32 -> f16 convert (4 elems/thread)
// ---------------------------------------------------------------------------
__global__ __launch_bounds__(256) void cvt_f32_f16(const float* __restrict__ in,
                                                   u16* __restrict__ out, int n4) {
  int i = blockIdx.x * 256 + threadIdx.x;
  if (i >= n4) return;
  f32x4 v = *(const f32x4*)(in + (size_t)i * 4);
  u16x4 o;
  o[0] = f2h(v[0]); o[1] = f2h(v[1]); o[2] = f2h(v[2]); o[3] = f2h(v[3]);
  *(u16x4*)(out + (size_t)i * 4) = o;
}

// ---------------------------------------------------------------------------
// 256x256 GEMM, double-buffered LDS (128KB), single barrier per K-tile
// (round-12 known-good, 16x16x32 MFMA, zero bank conflicts).
// vtg: V cols stored transposed; ropeTab: rope fused (pair exchange via DPP).
// ---------------------------------------------------------------------------
static __device__ __forceinline__ void store_out(float* C, size_t idx, float v) { C[idx] = v; }
static __device__ __forceinline__ void store_out(u16* C, size_t idx, float v) { C[idx] = f2h(v); }

static __device__ __forceinline__ void stageA(const u16* __restrict__ Ab, int K, int kt,
                                              u16* As, int mh, int t) {
  int hf = t >> 8;
  int tt = t & 255;
  int row = hf * 128 + mh * 32 + (tt >> 3);
  int slot = tt & 7;
  gload_lds16(Ab + (size_t)row * K + kt + ((slot ^ (row & 7)) << 3),
              (char*)As + hf * 16384 + mh * 4096 + tt * 16);
}
static __device__ __forceinline__ void stageB(const u16* __restrict__ Bb, int K, int kt,
                                              u16* Bs, int j, int t) {
  int row = j * 64 + (t >> 3);
  int slot = t & 7;
  gload_lds16(Bb + (size_t)row * K + kt + ((slot ^ (row & 7)) << 3),
              (char*)Bs + j * 8192 + t * 16);
}

#define LOAD_BF(BS)                                                              \
  _Pragma("unroll") for (int nf = 0; nf < 4; ++nf)                               \
    _Pragma("unroll") for (int kk = 0; kk < 2; ++kk) {                           \
      int row = wn * 64 + nf * 16 + l15;                                         \
      int slot = (kk * 4 + g) ^ (l15 & 7);                                       \
      bf[nf][kk] = *(const half8*)((const char*)(BS) + row * 128 + slot * 16);   \
    }

#define LOAD_AF(AF, AS, Q)                                                       \
  _Pragma("unroll") for (int mf = 0; mf < 2; ++mf)                               \
    _Pragma("unroll") for (int kk = 0; kk < 2; ++kk) {                           \
      int row = wm * 128 + ((Q) * 2 + mf) * 16 + l15;                            \
      int slot = (kk * 4 + g) ^ (l15 & 7);                                       \
      (AF)[mf][kk] = *(const half8*)((const char*)(AS) + row * 128 + slot * 16); \
    }

#define MFMA_BURST(AF, Q)                                                        \
  __builtin_amdgcn_s_setprio(1);                                                 \
  _Pragma("unroll") for (int kk = 0; kk < 2; ++kk)                               \
    _Pragma("unroll") for (int mf = 0; mf < 2; ++mf)                             \
      _Pragma("unroll") for (int nf = 0; nf < 4; ++nf)                           \
        acc[(Q) * 2 + mf][nf] = __builtin_amdgcn_mfma_f32_16x16x32_f16(          \
            (AF)[mf][kk], bf[nf][kk], acc[(Q) * 2 + mf][nf], 0, 0, 0);           \
  __builtin_amdgcn_s_setprio(0);

template <typename OutT>
__global__ __launch_bounds__(512, 2) void gemm256(const u16* __restrict__ A,
                                                  const u16* __restrict__ Bt,
                                                  OutT* __restrict__ C,
                                                  u16* __restrict__ vtg,
                                                  const float* __restrict__ ropeTab,
                                                  int M, int N, int K, int nbn,
                                                  int ldc) {
  __shared__ u16 lds[4][16384];
  const int t = threadIdx.x;
  const int lane = t & 63;
  const int wid = t >> 6;
  const int g = lane >> 4, l15 = lane & 15;
  const int wm = wid >> 2, wn = wid & 3;
  const int nwg = gridDim.x;
  const int bid = blockIdx.x;
  const int wgid = (bid & 7) * (nwg >> 3) + (bid >> 3);  // XCD swizzle (nwg%8==0)
  const int bm = wgid / nbn, bn = wgid % nbn;
  const u16* Ab = A + (size_t)bm * 256 * K;
  const u16* Bb = Bt + (size_t)bn * 256 * K;
  f32x4 acc[8][4] = {};

  stageA(Ab, K, 0, lds[0], 0, t);
  stageA(Ab, K, 0, lds[0], 1, t);
  stageA(Ab, K, 0, lds[0], 2, t);
  stageA(Ab, K, 0, lds[0], 3, t);
  stageB(Bb, K, 0, lds[1], 0, t);
  stageB(Bb, K, 0, lds[1], 1, t);
  stageB(Bb, K, 0, lds[1], 2, t);
  stageB(Bb, K, 0, lds[1], 3, t);
  asm volatile("s_waitcnt vmcnt(0)" ::: "memory");
  __builtin_amdgcn_s_barrier();

  const int nt = K >> 6;
  for (int i = 0; i < nt; ++i) {
    u16* As  = lds[(i & 1) << 1];
    u16* Bs  = lds[((i & 1) << 1) + 1];
    u16* Asn = lds[((i + 1) & 1) << 1];
    u16* Bsn = lds[(((i + 1) & 1) << 1) + 1];
    int k1 = (i + 1) << 6; if (k1 >= K) k1 = 0;  // tail: staged, never read
    half8 bf[4][2], afA[2][2], afB[2][2];
    LOAD_BF(Bs);
    LOAD_AF(afA, As, 0);
    stageB(Bb, K, k1, Bsn, 0, t);
    stageB(Bb, K, k1, Bsn, 1, t);
    stageB(Bb, K, k1, Bsn, 2, t);
    stageB(Bb, K, k1, Bsn, 3, t);
    stageA(Ab, K, k1, Asn, 0, t);
    stageA(Ab, K, k1, Asn, 1, t);
    stageA(Ab, K, k1, Asn, 2, t);
    stageA(Ab, K, k1, Asn, 3, t);
    LOAD_AF(afB, As, 1);
    MFMA_BURST(afA, 0);
    LOAD_AF(afA, As, 2);
    MFMA_BURST(afB, 1);
    LOAD_AF(afB, As, 3);
    MFMA_BURST(afA, 2);
    MFMA_BURST(afB, 3);
    asm volatile("s_waitcnt vmcnt(0) lgkmcnt(0)" ::: "memory");
    __builtin_amdgcn_s_barrier();
  }

  if (vtg && bn >= 32) {
#pragma unroll
    for (int mf = 0; mf < 8; ++mf) {
      int row0 = bm * 256 + wm * 128 + mf * 16 + 4 * g;
      int bI = row0 >> 11, t0 = row0 & 2047;
#pragma unroll
      for (int nf = 0; nf < 4; ++nf) {
        int vcol = bn * 256 + wn * 64 + nf * 16 + l15 - 8192;
        int hI = vcol >> 7, dI = vcol & 127;
        u16x4 o;
#pragma unroll
        for (int r = 0; r < 4; ++r) o[r] = f2h(acc[mf][nf][r]);
        *(u16x4*)(vtg + ((size_t)(bI * 32 + hI) * 128 + dI) * 2048 + t0) = o;
      }
    }
  } else {
    if (ropeTab) {
      const bool even = (l15 & 1) == 0;
#pragma unroll
      for (int mf = 0; mf < 8; ++mf) {
        int row0 = bm * 256 + wm * 128 + mf * 16 + 4 * g;
#pragma unroll
        for (int nf = 0; nf < 4; ++nf) {
          int col = bn * 256 + wn * 64 + nf * 16 + l15;
          int p = (col & 127) >> 1;
#pragma unroll
          for (int r = 0; r < 4; ++r) {
            int tpos = (row0 + r) & 2047;
            float ang = ropeTab[tpos * 64 + p];
            float sn, cs;
            __sincosf(ang, &sn, &cs);
            float own = acc[mf][nf][r];
            float xp = dppf<0xB1>(own);  // lane^1 partner via DPP (VALU pipe)
            acc[mf][nf][r] = even ? (own * cs - xp * sn) : (xp * sn + own * cs);
          }
        }
      }
    }
#pragma unroll
    for (int mf = 0; mf < 8; ++mf) {
      int row0 = bm * 256 + wm * 128 + mf * 16 + 4 * g;
#pragma unroll
      for (int nf = 0; nf < 4; ++nf) {
        int col = bn * 256 + wn * 64 + nf * 16 + l15;
#pragma unroll
        for (int r = 0; r < 4; ++r)
          store_out(C, (size_t)(row0 + r) * ldc + col, acc[mf][nf][r]);
      }
    }
  }
}

// ---------------------------------------------------------------------------
// Adapter k/v: acc[j,n] = sum_k prompt[j,k] * w_attn[k, 4096+n]
// ---------------------------------------------------------------------------
__global__ __launch_bounds__(256) void adaption_kv_kernel(const float* __restrict__ prompt,
                                                          const float* __restrict__ w_attn,
                                                          u16* __restrict__ akbuf,
                                                          u16* __restrict__ avbuf) {
  __shared__ float pl[10][512];
  __shared__ float red[8][10][32];
  const int t = threadIdx.x;
  const int tc = t & 31, tk = t >> 5;
  const int n = blockIdx.x * 32 + tc;  // 0..8191
  float acc[10] = {};
  for (int k0 = 0; k0 < 4096; k0 += 512) {
    __syncthreads();
#pragma unroll
    for (int i = 0; i < 20; ++i) {
      int idx = t + 256 * i;  // < 5120
      int j = idx >> 9, kk = idx & 511;
      pl[j][kk] = prompt[(size_t)j * 4096 + k0 + kk];
    }
    __syncthreads();
    for (int kk = tk; kk < 512; kk += 8) {
      float wv = w_attn[(size_t)(k0 + kk) * 12288 + 4096 + n];
#pragma unroll
      for (int j = 0; j < 10; ++j) acc[j] += pl[j][kk] * wv;
    }
  }
  __syncthreads();
#pragma unroll
  for (int j = 0; j < 10; ++j) red[tk][j][tc] = acc[j];
  __syncthreads();
  if (tk == 0) {
    float s[10];
#pragma unroll
    for (int j = 0; j < 10; ++j) {
      s[j] = 0.f;
#pragma unroll
      for (int q = 0; q < 8; ++q) s[j] += red[q][j][tc];
    }
    u16* dst;
    int hh, d;
    if (n < 4096) { dst = akbuf; hh = n >> 7; d = n & 127; }
    else          { dst = avbuf; hh = (n - 4096) >> 7; d = n & 127; }
#pragma unroll
    for (int j = 0; j < 16; ++j)
      dst[(size_t)(hh * 16 + j) * 128 + d] = (j < 10) ? f2h(s[j]) : (u16)0;
  }
}

// ---------------------------------------------------------------------------
// Flash attention + adapter epilogue (round-12 known-good, unchanged).
// 4 waves, 64 q rows/block, KV tile 64. LDS 40KB -> 4 blocks/CU. DPP softmax.
// ---------------------------------------------------------------------------
__global__ __launch_bounds__(256) void attn_kernel(const u16* __restrict__ qk,
                                                   const u16* __restrict__ vt,
                                                   const u16* __restrict__ akbuf,
                                                   const u16* __restrict__ avbuf,
                                                   const float* __restrict__ gating,
                                                   u16* __restrict__ y) {
  __shared__ u16 Kl[64 * 128];
  __shared__ u16 Vtl[128 * 64];
  __shared__ u16 Pl[4][16 * 64];

  const int t = threadIdx.x;
  const int lane = t & 63, w = t >> 6;
  const int g = lane >> 4, l15 = lane & 15;
  const int bx = blockIdx.x;
  const int qb = 31 - (bx >> 6);          // long blocks first
  const int bh = bx & 63, b = bh >> 5, h = bh & 31;
  const int ldq = 8192;
  const u16* Qg = qk + (size_t)b * 2048 * ldq + h * 128;
  const u16* Kg = Qg + 4096;
  const u16* VtG = vt + (size_t)(b * 32 + h) * 128 * 2048;
  u16* AKb = &Pl[0][0];

  // stage Q (64x128) into Kl and AK (16x128) into P region via global_load_lds
#pragma unroll
  for (int i = 0; i < 4; ++i) {
    int c = t + 256 * i;
    int row = c >> 4, slot = c & 15;
    gload_lds16(Qg + (size_t)(qb * 64 + row) * ldq + ((slot ^ (row & 15)) << 3),
                (char*)Kl + c * 16);
  }
  {
    int row = t >> 4, slot = t & 15;
    gload_lds16(akbuf + (size_t)(h * 16 + row) * 128 + ((slot ^ row) << 3),
                (char*)AKb + t * 16);
  }
  __syncthreads();

  half8 qf[4];
#pragma unroll
  for (int kk = 0; kk < 4; ++kk) {
    int slot = (kk * 4 + g) ^ l15;
    qf[kk] = *(const half8*)((const char*)Kl + (w * 16 + l15) * 256 + (slot << 4));
  }
  f32x4 sa = {};
#pragma unroll
  for (int kk = 0; kk < 4; ++kk) {
    int slot = (kk * 4 + g) ^ l15;
    half8 af = *(const half8*)((const char*)AKb + l15 * 256 + (slot << 4));
    sa = __builtin_amdgcn_mfma_f32_16x16x32_f16(qf[kk], af, sa, 0, 0, 0);
  }
  __syncthreads();

  f32x4 acc[8] = {};
  float mrun[4], lrun[4];
#pragma unroll
  for (int r = 0; r < 4; ++r) { mrun[r] = -1e30f; lrun[r] = 0.f; }

  for (int kvt = 0; kvt <= qb; ++kvt) {
#pragma unroll
    for (int i = 0; i < 4; ++i) {
      int c = t + 256 * i;
      int row = c >> 4, slot = c & 15;
      gload_lds16(Kg + (size_t)(kvt * 64 + row) * ldq + ((slot ^ (row & 15)) << 3),
                  (char*)Kl + c * 16);
    }
#pragma unroll
    for (int i = 0; i < 4; ++i) {
      int c = t + 256 * i;
      int d = c >> 3, s3 = c & 7;
      gload_lds16(VtG + (size_t)d * 2048 + kvt * 64 + ((s3 ^ (d & 7)) << 3),
                  (char*)Vtl + c * 16);
    }
    __syncthreads();

    f32x4 s[4] = {};
#pragma unroll
    for (int nf = 0; nf < 4; ++nf) {
#pragma unroll
      for (int kk = 0; kk < 4; ++kk) {
        int slot = (kk * 4 + g) ^ l15;
        half8 kf = *(const half8*)((const char*)Kl + (nf * 16 + l15) * 256 + (slot << 4));
        s[nf] = __builtin_amdgcn_mfma_f32_16x16x32_f16(qf[kk], kf, s[nf], 0, 0, 0);
      }
    }
    const float sc = 0.08838834764831843f;  // 1/sqrt(128)
    if (kvt == qb) {
#pragma unroll
      for (int nf = 0; nf < 4; ++nf)
#pragma unroll
        for (int r = 0; r < 4; ++r) {
          int kv = nf * 16 + l15;
          int qq = w * 16 + 4 * g + r;
          float v = s[nf][r] * sc;
          s[nf][r] = (kv <= qq) ? v : -1e30f;
        }
    } else {
#pragma unroll
      for (int nf = 0; nf < 4; ++nf)
#pragma unroll
        for (int r = 0; r < 4; ++r) s[nf][r] *= sc;
    }

    // online softmax: 16-lane reduce fully on VALU (DPP)
    float alpha[4];
#pragma unroll
    for (int r = 0; r < 4; ++r) {
      float mt = fmaxf(fmaxf(s[0][r], s[1][r]), fmaxf(s[2][r], s[3][r]));
      mt = red16_max(mt);
      float mn = fmaxf(mrun[r], mt);
      alpha[r] = __expf(mrun[r] - mn);
      mrun[r] = mn;
      float rs = 0.f;
#pragma unroll
      for (int nf = 0; nf < 4; ++nf) {
        float p = __expf(s[nf][r] - mn);
        s[nf][r] = p;
        rs += p;
      }
      rs = red16_sum(rs);
      lrun[r] = lrun[r] * alpha[r] + rs;
    }
#pragma unroll
    for (int nd = 0; nd < 8; ++nd)
#pragma unroll
      for (int r = 0; r < 4; ++r)
        acc[nd][r] *= alpha[r];

#pragma unroll
    for (int nf = 0; nf < 4; ++nf)
#pragma unroll
      for (int r = 0; r < 4; ++r) {
        int qq = 4 * g + r;
        int kv = nf * 16 + l15;
        int byteoff = (qq * 128 + kv * 2) ^ ((qq & 7) << 4);
        *(u16*)((char*)Pl[w] + byteoff) = f2h(s[nf][r]);
      }

#pragma unroll
    for (int kk2 = 0; kk2 < 2; ++kk2) {
      int pslot = (kk2 * 4 + g) ^ (l15 & 7);
      half8 pf = *(const half8*)((const char*)Pl[w] + l15 * 128 + (pslot << 4));
#pragma unroll
      for (int nd = 0; nd < 8; ++nd) {
        int d = nd * 16 + l15;
        int slot = (kk2 * 4 + g) ^ (d & 7);
        half8 vf = *(const half8*)((const char*)Vtl + d * 128 + (slot << 4));
        acc[nd] = __builtin_amdgcn_mfma_f32_16x16x32_f16(pf, vf, acc[nd], 0, 0, 0);
      }
    }
    __syncthreads();
  }

  // ---- epilogue ----
  {
    int d = t >> 1;
    int jb = (t & 1) << 4;
#pragma unroll
    for (int i = 0; i < 16; ++i) {
      int j = jb + i;
      u16 v = (j < 16) ? avbuf[(size_t)(h * 16 + j) * 128 + d] : (u16)0;
      int byteoff = (d * 64 + j * 2) ^ ((d & 3) << 4);
      *(u16*)((char*)Kl + byteoff) = v;
    }
  }
  __syncthreads();

  float ga = gating[0];
  float pa4[4];
#pragma unroll
  for (int r = 0; r < 4; ++r) {
    float v = sa[r] * (1.0f / 64.0f);
    if (l15 >= 10) v = -1e30f;
    float mt = red16_max(v);
    float p = __expf(v - mt);
    float rs = red16_sum(p);
    pa4[r] = p / rs * ga;
  }
#pragma unroll
  for (int r = 0; r < 4; ++r) {
    float inv = 1.0f / lrun[r];
#pragma unroll
    for (int nd = 0; nd < 8; ++nd)
      acc[nd][r] *= inv;
  }
#pragma unroll
  for (int r = 0; r < 4; ++r) {
    int qq = 4 * g + r;
    int b1 = (qq * 128 + l15 * 2) ^ ((qq & 7) << 4);
    *(u16*)((char*)Pl[w] + b1) = f2h(pa4[r]);
    int b2 = (qq * 128 + (16 + l15) * 2) ^ ((qq & 7) << 4);
    *(u16*)((char*)Pl[w] + b2) = 0;
  }
  {
    int pslot = g ^ (l15 & 7);
    half8 pf = *(const half8*)((const char*)Pl[w] + l15 * 128 + (pslot << 4));
#pragma unroll
    for (int nd = 0; nd < 8; ++nd) {
      int d = nd * 16 + l15;
      int byteoff = (d * 64 + g * 16) ^ ((d & 3) << 4);
      half8 avf = *(const half8*)((const char*)Kl + byteoff);
      acc[nd] = __builtin_amdgcn_mfma_f32_16x16x32_f16(pf, avf, acc[nd], 0, 0, 0);
    }
  }
#pragma unroll
  for (int nd = 0; nd < 8; ++nd) {
    int col = h * 128 + nd * 16 + l15;
#pragma unroll
    for (int r = 0; r < 4; ++r) {
      int row = qb * 64 + w * 16 + 4 * g + r;
      y[(size_t)(b * 2048 + row) * 4096 + col] = f2h(acc[nd][r]);
    }
  }
}

// ---------------------------------------------------------------------------
extern "C" void kernel_launch(void* const* d_in, const int* in_sizes, int n_in,
                              void* d_out, int out_size, void* d_ws, size_t ws_size,
                              hipStream_t stream) {
  (void)in_sizes; (void)n_in; (void)out_size; (void)ws_size;
  const float* x      = (const float*)d_in[0];
  const float* prompt = (const float*)d_in[1];
  const float* rope   = (const float*)d_in[2];
  const float* w_attn = (const float*)d_in[3];
  const float* w_proj = (const float*)d_in[4];
  const float* gating = (const float*)d_in[5];
  float* out = (float*)d_out;

  char* ws = (char*)d_ws;
  u16* WtA = (u16*)(ws);                     // 12288x4096 f16 (100663296 B)
  u16* Yb  = (u16*)(ws);                     // reuses WtA region after GEMM1
  u16* qk  = (u16*)(ws + 100663296);         // 4096x8192 f16 (67108864 B)
  u16* VtG = (u16*)(ws + 167772160);         // 2x32x128x2048 f16 (33554432 B)
  u16* xb  = (u16*)(ws + 201326592);         // 4096x4096 f16
  u16* WtP = (u16*)(ws + 201326592);         // reuses xb region after GEMM1
  u16* akb = (u16*)(ws + 234881024);         // 32x16x128 f16
  u16* avb = (u16*)(ws + 234881024 + 131072);

  transpose_cvt<<<dim3(192, 64), dim3(256), 0, stream>>>(w_attn, WtA, 4096, 12288);
  cvt_f32_f16<<<dim3(16384), dim3(256), 0, stream>>>(x, xb, 4194304);
  gemm256<u16><<<dim3(768), dim3(512), 0, stream>>>(xb, WtA, qk, VtG, rope,
                                                    4096, 12288, 4096, 48, 8192);
  adaption_kv_kernel<<<dim3(256), dim3(256), 0, stream>>>(prompt, w_attn, akb, avb);
  attn_kernel<<<dim3(2048), dim3(256), 0, stream>>>(qk, VtG, akb, avb, gating, Yb);
  transpose_cvt<<<dim3(64, 64), dim3(256), 0, stream>>>(w_proj, WtP, 4096, 4096);
  gemm256<float><<<dim3(256), dim3(512), 0, stream>>>(Yb, WtP, out, nullptr, nullptr,
                                                      4096, 4096, 4096, 16, 4096);
}